// Round 4
// baseline (129.183 us; speedup 1.0000x reference)
//
#include <hip/hip_runtime.h>

// ---------------------------------------------------------------------------
// MLP-GNN fused op for MI355X (gfx950).
//   v  = tanh(tanh(z @ cw1^T + cb1) @ cw2^T + cb2)                    [N,128]
//   vn = tanh(tanh([z|z_] @ nw1^T + nb1) @ nw2^T + nb2).sum(axis=K)   [N,128]
//   dc = [v | vn] @ ow^T + ob                                         [N,64]
// bf16 MFMA (16x16x32), f32 accum. 3 kernels:
//   cur_kernel:  v -> feat[:,0:128]  AND  u1[n][h] = z@nw1[:,:128]^T + nb1
//   nbr_kernel:  vn -> feat[:,128:256].
//     R4: depth-2 z_ prefetch (rA/rB ping-pong, x2-unrolled loop) so a 2-tile
//     HBM backlog persists through compute phases (breaks the lockstep
//     mem/compute alternation); tanh trimmed to 5 instr w/ bias folded into
//     the exp2 arg; L2 neighbor-sum via sum-of-rcp (saves 32 fma/thread/iter).
//   out_kernel:  dc -> d_out (f32)
// ---------------------------------------------------------------------------

typedef __bf16 bf16;
typedef __bf16 bf16x2 __attribute__((ext_vector_type(2)));
typedef __bf16 bf16x4 __attribute__((ext_vector_type(4)));
typedef __bf16 bf16x8 __attribute__((ext_vector_type(8)));
typedef float  f32x4  __attribute__((ext_vector_type(4)));

#define MFMA(a, b, c) __builtin_amdgcn_mfma_f32_16x16x32_bf16((a), (b), (c), 0, 0, 0)

#define C2LOG2E 2.885390081777927f   // 2*log2(e)

// Workgroup barrier WITHOUT the vmcnt(0) drain __syncthreads() implies.
__device__ __forceinline__ void block_sync_lds() {
    asm volatile("s_waitcnt lgkmcnt(0)\n\ts_barrier" ::: "memory");
}

// tanh(x) = 1 - 2/(exp2(2*log2e*x)+1) — valid for all signs, inf-safe.
__device__ __forceinline__ float fast_tanh(float x) {
    float t = __builtin_amdgcn_exp2f(x * C2LOG2E);
    return 1.0f - 2.0f * __builtin_amdgcn_rcpf(t + 1.0f);
}
// tanh(acc + u) with pre-scaled bias uc = u*C2LOG2E: one fma for the arg.
__device__ __forceinline__ float fast_tanh_fb(float acc, float uc) {
    float t = __builtin_amdgcn_exp2f(__builtin_fmaf(acc, C2LOG2E, uc));
    return 1.0f - 2.0f * __builtin_amdgcn_rcpf(t + 1.0f);
}
// r-part only: rcp(exp2(fma)+1); caller uses sum = count - 2*sum(r).
__device__ __forceinline__ float tanh_rpart(float acc, float uc) {
    float t = __builtin_amdgcn_exp2f(__builtin_fmaf(acc, C2LOG2E, uc));
    return __builtin_amdgcn_rcpf(t + 1.0f);
}

__device__ __forceinline__ bf16x8 cvt8(f32x4 a, f32x4 b) {
    bf16x8 r;
    r[0] = (bf16)a[0]; r[1] = (bf16)a[1]; r[2] = (bf16)a[2]; r[3] = (bf16)a[3];
    r[4] = (bf16)b[0]; r[5] = (bf16)b[1]; r[6] = (bf16)b[2]; r[7] = (bf16)b[3];
    return r;
}

// LDS tiles: 128-bf16 rows (256 B = 16 x 16B chunks), chunk-XOR swizzle.
__device__ __forceinline__ int swz128(int row, int col) {
    int c = (col >> 3) ^ (row & 15);
    return row * 256 + c * 16 + (col & 7) * 2;
}
// 256-bf16 rows (512 B = 32 chunks)
__device__ __forceinline__ int swz256(int row, int col) {
    int c = (col >> 3) ^ (row & 15);
    return row * 512 + c * 16 + (col & 7) * 2;
}

__device__ __forceinline__ void st_pair(char* base, int off, float a, float b) {
    bf16x2 p = {(bf16)a, (bf16)b};
    *(bf16x2*)(base + off) = p;
}

// ---------------------------------------------------------------------------
// Kernel B: neighbor branch. One PAIR (2p, 2p+1) per iteration, 32 z_ rows
// each. L1 operand-swapped over the z_-half; z-half arrives as bias u1[n][h].
// Depth-2 register prefetch of z_ tiles (rA/rB), depth-1 for u1.
// ---------------------------------------------------------------------------
__global__ __launch_bounds__(256, 2) void nbr_kernel(
    const float* __restrict__ zn, const float* __restrict__ u1,
    const float* __restrict__ w1, const float* __restrict__ w2,
    const float* __restrict__ b2,
    bf16* __restrict__ feat, int NP)
{
    __shared__ char zc_lds[2][32 * 256];
    __shared__ char h1_lds[2][32 * 256];

    const int t = threadIdx.x;
    const int wv = t >> 6, lane = t & 63, g = lane >> 4, li = lane & 15;
    const int hbase = wv * 32;

    // z_-half of W1 (cols 128..255) as swapped-L1 A-frags
    bf16x8 w1f[2][4];
#pragma unroll
    for (int ht = 0; ht < 2; ++ht)
#pragma unroll
        for (int kb = 0; kb < 4; ++kb) {
            const float* p = w1 + (size_t)(hbase + 16*ht + li) * 256 + 128 + kb*32 + 8*g;
            w1f[ht][kb] = cvt8(*(const f32x4*)p, *(const f32x4*)(p + 4));
        }
    bf16x8 w2f[2][4];
#pragma unroll
    for (int nt = 0; nt < 2; ++nt)
#pragma unroll
        for (int kb = 0; kb < 4; ++kb) {
            const float* p = w2 + (size_t)(hbase + 16*nt + li) * 128 + kb*32 + 8*g;
            w2f[nt][kb] = cvt8(*(const f32x4*)p, *(const f32x4*)(p + 4));
        }
    // pre-scaled L2 bias (folded into the exp2 argument)
    float bc2v[2];
#pragma unroll
    for (int nt = 0; nt < 2; ++nt) bc2v[nt] = b2[hbase + 16*nt + li] * C2LOG2E;

    const int sm  = t >> 3;        // staging row 0..31
    const int scf = (t & 7) * 16;  // staging col (floats)
    const int str = gridDim.x;

    f32x4 rA[2][4], rB[2][4];  // two z_ tile slots (depth-2)
    f32x4 uu[2][2];            // u1 bias (depth-1)

    auto load_zn = [&](f32x4 (&R)[2][4], int pp) {
#pragma unroll
        for (int j = 0; j < 2; ++j) {
            const float* src = zn + ((size_t)(2*pp + j) * 32 + sm) * 128 + scf;
#pragma unroll
            for (int q = 0; q < 4; ++q) R[j][q] = *(const f32x4*)(src + 4*q);
        }
    };
    auto load_u = [&](int pp) {
#pragma unroll
        for (int j = 0; j < 2; ++j)
#pragma unroll
            for (int ht = 0; ht < 2; ++ht)
                uu[j][ht] = *(const f32x4*)(u1 + (size_t)(2*pp + j) * 128 + hbase + 16*ht + 4*g);
    };

    const int p0 = blockIdx.x;
    load_zn(rA, p0);
    if (p0 + str < NP) load_zn(rB, p0 + str);
    load_u(p0);

    const f32x4 vzero = {0.f, 0.f, 0.f, 0.f};

    auto iter_body = [&](f32x4 (&R)[2][4], int p) {
        // ---- LDS write of tile p (counted vmcnt wait on R here) ----
#pragma unroll
        for (int j = 0; j < 2; ++j) {
            *(bf16x8*)(zc_lds[j] + swz128(sm, scf))     = cvt8(R[j][0], R[j][1]);
            *(bf16x8*)(zc_lds[j] + swz128(sm, scf + 8)) = cvt8(R[j][2], R[j][3]);
        }
        block_sync_lds();   // B1 (no vmcnt drain)

        // ---- refill this slot with tile p+2*str (2 iterations of slack) ----
        const int pz = p + 2*str;
        if (pz < NP) load_zn(R, pz);

        // ---- layer 1 (swapped, z_-half): 32 MFMAs, 8 indep chains ----
        f32x4 acc1[2][2][2];
#pragma unroll
        for (int j = 0; j < 2; ++j)
#pragma unroll
            for (int a = 0; a < 2; ++a)
#pragma unroll
                for (int b = 0; b < 2; ++b) acc1[j][a][b] = vzero;

        __builtin_amdgcn_s_setprio(1);
#pragma unroll
        for (int kb = 0; kb < 4; ++kb) {
            bf16x8 bz[2][2];
#pragma unroll
            for (int j = 0; j < 2; ++j)
#pragma unroll
                for (int mt = 0; mt < 2; ++mt)
                    bz[j][mt] = *(const bf16x8*)(zc_lds[j] + swz128(16*mt + li, kb*32 + 8*g));
#pragma unroll
            for (int j = 0; j < 2; ++j)
#pragma unroll
                for (int ht = 0; ht < 2; ++ht)
#pragma unroll
                    for (int mt = 0; mt < 2; ++mt)
                        acc1[j][ht][mt] = MFMA(w1f[ht][kb], bz[j][mt], acc1[j][ht][mt]);
        }
        __builtin_amdgcn_s_setprio(0);

        // ---- finish L1: tanh(acc + u1) -> h1 (bias pre-scaled, b64 stores) --
#pragma unroll
        for (int j = 0; j < 2; ++j)
#pragma unroll
            for (int ht = 0; ht < 2; ++ht) {
                f32x4 uc = uu[j][ht] * C2LOG2E;
#pragma unroll
                for (int mt = 0; mt < 2; ++mt) {
                    float v0 = fast_tanh_fb(acc1[j][ht][mt][0], uc[0]);
                    float v1 = fast_tanh_fb(acc1[j][ht][mt][1], uc[1]);
                    float v2 = fast_tanh_fb(acc1[j][ht][mt][2], uc[2]);
                    float v3 = fast_tanh_fb(acc1[j][ht][mt][3], uc[3]);
                    int m = 16*mt + li;
                    int h = hbase + 16*ht + 4*g;
                    bf16x4 q = {(bf16)v0, (bf16)v1, (bf16)v2, (bf16)v3};
                    *(bf16x4*)(h1_lds[j] + swz128(m, h)) = q;
                }
            }

        // ---- refill u1 for tile p+str (one iteration of slack) ----
        const int pu = p + str;
        if (pu < NP) load_u(pu);
        block_sync_lds();   // B2 (no vmcnt drain)

        // ---- layer 2 (normal): 32 MFMAs, 8 indep chains ----
        f32x4 acc2[2][2][2];
#pragma unroll
        for (int j = 0; j < 2; ++j)
#pragma unroll
            for (int a = 0; a < 2; ++a)
#pragma unroll
                for (int b = 0; b < 2; ++b) acc2[j][a][b] = vzero;

        __builtin_amdgcn_s_setprio(1);
#pragma unroll
        for (int kb = 0; kb < 4; ++kb) {
            bf16x8 ah[2][2];
#pragma unroll
            for (int j = 0; j < 2; ++j)
#pragma unroll
                for (int mt = 0; mt < 2; ++mt)
                    ah[j][mt] = *(const bf16x8*)(h1_lds[j] + swz128(16*mt + li, kb*32 + 8*g));
#pragma unroll
            for (int j = 0; j < 2; ++j)
#pragma unroll
                for (int mt = 0; mt < 2; ++mt)
#pragma unroll
                    for (int nt = 0; nt < 2; ++nt)
                        acc2[j][mt][nt] = MFMA(ah[j][mt], w2f[nt][kb], acc2[j][mt][nt]);
        }
        __builtin_amdgcn_s_setprio(0);

        // ---- finish L2: sum tanh over 32 rows = 32 - 2*sum(r) ----
#pragma unroll
        for (int j = 0; j < 2; ++j) {
            float sr0 = 0.f, sr1 = 0.f;
#pragma unroll
            for (int mt = 0; mt < 2; ++mt)
#pragma unroll
                for (int rr = 0; rr < 4; ++rr) {
                    sr0 += tanh_rpart(acc2[j][mt][0][rr], bc2v[0]);
                    sr1 += tanh_rpart(acc2[j][mt][1][rr], bc2v[1]);
                }
            sr0 += __shfl_xor(sr0, 16); sr0 += __shfl_xor(sr0, 32);
            sr1 += __shfl_xor(sr1, 16); sr1 += __shfl_xor(sr1, 32);
            if (lane < 16) {
                float s0 = __builtin_fmaf(-2.f, sr0, 32.f);
                float s1 = __builtin_fmaf(-2.f, sr1, 32.f);
                bf16* dst = feat + (size_t)(2*p + j) * 256 + 128 + hbase + lane;
                dst[0]  = (bf16)s0;
                dst[16] = (bf16)s1;
            }
        }
    };

    for (int p = p0; p < NP; ) {
        iter_body(rA, p);
        p += str;
        if (p >= NP) break;
        iter_body(rB, p);
        p += str;
    }
}

// ---------------------------------------------------------------------------
// Kernel A: cur branch (feat[:,0:128]) + u1 = z @ nw1[:,:128]^T + nb1.
// ---------------------------------------------------------------------------
__global__ __launch_bounds__(256, 2) void cur_kernel(
    const float* __restrict__ z,
    const float* __restrict__ w1, const float* __restrict__ b1,
    const float* __restrict__ w2, const float* __restrict__ b2,
    const float* __restrict__ nw1, const float* __restrict__ nb1,
    bf16* __restrict__ feat, float* __restrict__ u1, int N)
{
    __shared__ char z_lds[64 * 256];
    __shared__ char h1_lds[64 * 256];

    const int t = threadIdx.x;
    const int wv = t >> 6, lane = t & 63, g = lane >> 4, li = lane & 15;
    const int hbase = wv * 32;
    const int n0 = blockIdx.x * 64;

    bf16x8 w1f[2][4], w2f[2][4], wzf[2][4];
#pragma unroll
    for (int ht = 0; ht < 2; ++ht)
#pragma unroll
        for (int kb = 0; kb < 4; ++kb) {
            const float* p1 = w1 + (size_t)(hbase + 16*ht + li) * 128 + kb*32 + 8*g;
            w1f[ht][kb] = cvt8(*(const f32x4*)p1, *(const f32x4*)(p1 + 4));
            const float* p2 = w2 + (size_t)(hbase + 16*ht + li) * 128 + kb*32 + 8*g;
            w2f[ht][kb] = cvt8(*(const f32x4*)p2, *(const f32x4*)(p2 + 4));
            const float* p3 = nw1 + (size_t)(hbase + 16*ht + li) * 256 + kb*32 + 8*g;
            wzf[ht][kb] = cvt8(*(const f32x4*)p3, *(const f32x4*)(p3 + 4));
        }
    float b1v[2][4], b2v[2][4], bnv[2][4];
#pragma unroll
    for (int ht = 0; ht < 2; ++ht)
#pragma unroll
        for (int rr = 0; rr < 4; ++rr) {
            b1v[ht][rr] = b1[hbase + 16*ht + 4*g + rr];
            b2v[ht][rr] = b2[hbase + 16*ht + 4*g + rr];
            bnv[ht][rr] = nb1[hbase + 16*ht + 4*g + rr];
        }

    // stage 64 z rows (clamped for tail block)
    {
        int m = t >> 2;
        int c0 = (t & 3) * 32;
        int row = n0 + m; if (row > N - 1) row = N - 1;
        const float* src = z + (size_t)row * 128 + c0;
#pragma unroll
        for (int q = 0; q < 4; ++q) {
            f32x4 a = *(const f32x4*)(src + 8*q);
            f32x4 b = *(const f32x4*)(src + 8*q + 4);
            *(bf16x8*)(z_lds + swz128(m, c0 + 8*q)) = cvt8(a, b);
        }
    }
    __syncthreads();

    const f32x4 vzero = {0.f, 0.f, 0.f, 0.f};
    f32x4 acc1[2][4], accz[2][4];
#pragma unroll
    for (int a = 0; a < 2; ++a)
#pragma unroll
        for (int b = 0; b < 4; ++b) { acc1[a][b] = vzero; accz[a][b] = vzero; }

#pragma unroll
    for (int kb = 0; kb < 4; ++kb) {
        bf16x8 bz[4];
#pragma unroll
        for (int mt = 0; mt < 4; ++mt)
            bz[mt] = *(const bf16x8*)(z_lds + swz128(16*mt + li, kb*32 + 8*g));
#pragma unroll
        for (int ht = 0; ht < 2; ++ht)
#pragma unroll
            for (int mt = 0; mt < 4; ++mt) {
                acc1[ht][mt] = MFMA(w1f[ht][kb], bz[mt], acc1[ht][mt]);
                accz[ht][mt] = MFMA(wzf[ht][kb], bz[mt], accz[ht][mt]);
            }
    }

    // u1 store (f32)
#pragma unroll
    for (int ht = 0; ht < 2; ++ht)
#pragma unroll
        for (int mt = 0; mt < 4; ++mt) {
            int row = n0 + 16*mt + li;
            if (row < N) {
                f32x4 v;
#pragma unroll
                for (int rr = 0; rr < 4; ++rr) v[rr] = accz[ht][mt][rr] + bnv[ht][rr];
                *(f32x4*)(u1 + (size_t)row * 128 + hbase + 16*ht + 4*g) = v;
            }
        }

    // cur L1 finish -> h1
#pragma unroll
    for (int ht = 0; ht < 2; ++ht)
#pragma unroll
        for (int mt = 0; mt < 4; ++mt) {
            float v0 = fast_tanh(acc1[ht][mt][0] + b1v[ht][0]);
            float v1 = fast_tanh(acc1[ht][mt][1] + b1v[ht][1]);
            float v2 = fast_tanh(acc1[ht][mt][2] + b1v[ht][2]);
            float v3 = fast_tanh(acc1[ht][mt][3] + b1v[ht][3]);
            int m = 16*mt + li;
            int h = hbase + 16*ht + 4*g;
            st_pair(h1_lds, swz128(m, h),     v0, v1);
            st_pair(h1_lds, swz128(m, h + 2), v2, v3);
        }
    __syncthreads();

    f32x4 acc2[2][4];
#pragma unroll
    for (int a = 0; a < 2; ++a)
#pragma unroll
        for (int b = 0; b < 4; ++b) acc2[a][b] = vzero;

#pragma unroll
    for (int kb = 0; kb < 4; ++kb) {
        bf16x8 bh[4];
#pragma unroll
        for (int mt = 0; mt < 4; ++mt)
            bh[mt] = *(const bf16x8*)(h1_lds + swz128(16*mt + li, kb*32 + 8*g));
#pragma unroll
        for (int ht = 0; ht < 2; ++ht)
#pragma unroll
            for (int mt = 0; mt < 4; ++mt)
                acc2[ht][mt] = MFMA(w2f[ht][kb], bh[mt], acc2[ht][mt]);
    }
#pragma unroll
    for (int ht = 0; ht < 2; ++ht)
#pragma unroll
        for (int mt = 0; mt < 4; ++mt) {
            float v0 = fast_tanh(acc2[ht][mt][0] + b2v[ht][0]);
            float v1 = fast_tanh(acc2[ht][mt][1] + b2v[ht][1]);
            float v2 = fast_tanh(acc2[ht][mt][2] + b2v[ht][2]);
            float v3 = fast_tanh(acc2[ht][mt][3] + b2v[ht][3]);
            int row = n0 + 16*mt + li;
            if (row < N) {
                int h = hbase + 16*ht + 4*g;
                bf16* dst = feat + (size_t)row * 256 + h;
                bf16x2 p01 = {(bf16)v0, (bf16)v1};
                bf16x2 p23 = {(bf16)v2, (bf16)v3};
                *(bf16x2*)(dst)     = p01;
                *(bf16x2*)(dst + 2) = p23;
            }
        }
}

// ---------------------------------------------------------------------------
// Kernel C: dc = feat[N,256] @ ow^T + ob -> f32 out. 64 rows/block.
// ---------------------------------------------------------------------------
__global__ __launch_bounds__(256, 2) void out_kernel(
    const bf16* __restrict__ feat,
    const float* __restrict__ ow, const float* __restrict__ ob,
    float* __restrict__ out, int N)
{
    __shared__ char f_lds[64 * 512];

    const int t = threadIdx.x, wv = t >> 6, lane = t & 63, g = lane >> 4, li = lane & 15;
    const int cbase = wv * 16;
    const int n0 = blockIdx.x * 64;

    bf16x8 owf[8];
#pragma unroll
    for (int kb = 0; kb < 8; ++kb) {
        const float* p = ow + (size_t)(cbase + li) * 256 + kb*32 + 8*g;
        owf[kb] = cvt8(*(const f32x4*)p, *(const f32x4*)(p + 4));
    }
    float obv = ob[cbase + li];

    {
        int m = t >> 2;
        int c0 = (t & 3) * 64;
        int row = n0 + m; if (row > N - 1) row = N - 1;
        const bf16* src = feat + (size_t)row * 256 + c0;
#pragma unroll
        for (int q = 0; q < 8; ++q)
            *(bf16x8*)(f_lds + swz256(m, c0 + 8*q)) = *(const bf16x8*)(src + 8*q);
    }
    __syncthreads();

    const f32x4 vzero = {0.f, 0.f, 0.f, 0.f};
    f32x4 acc[4];
#pragma unroll
    for (int a = 0; a < 4; ++a) acc[a] = vzero;

#pragma unroll
    for (int kb = 0; kb < 8; ++kb) {
        bf16x8 af[4];
#pragma unroll
        for (int mt = 0; mt < 4; ++mt)
            af[mt] = *(const bf16x8*)(f_lds + swz256(16*mt + li, kb*32 + 8*g));
#pragma unroll
        for (int mt = 0; mt < 4; ++mt)
            acc[mt] = MFMA(af[mt], owf[kb], acc[mt]);
    }
#pragma unroll
    for (int mt = 0; mt < 4; ++mt)
#pragma unroll
        for (int rr = 0; rr < 4; ++rr) {
            int row = n0 + 16*mt + 4*g + rr;
            if (row < N) out[(size_t)row * 64 + cbase + li] = acc[mt][rr] + obv;
        }
}

// ---------------------------------------------------------------------------
extern "C" void kernel_launch(void* const* d_in, const int* in_sizes, int n_in,
                              void* d_out, int out_size, void* d_ws, size_t ws_size,
                              hipStream_t stream) {
    const float* z   = (const float*)d_in[0];
    const float* zn  = (const float*)d_in[1];
    const float* cw1 = (const float*)d_in[2];
    const float* cb1 = (const float*)d_in[3];
    const float* cw2 = (const float*)d_in[4];
    const float* cb2 = (const float*)d_in[5];
    const float* nw1 = (const float*)d_in[6];
    const float* nb1 = (const float*)d_in[7];
    const float* nw2 = (const float*)d_in[8];
    const float* nb2 = (const float*)d_in[9];
    const float* ow  = (const float*)d_in[10];
    const float* ob  = (const float*)d_in[11];
    float* out = (float*)d_out;

    const int N  = in_sizes[0] / 128;          // 20000
    const int NP = N / 2;                      // pairs for nbr_kernel
    const int nblk = (N + 63) / 64;            // 313

    bf16*  feat = (bf16*)d_ws;                            // [N][256] bf16
    float* u1   = (float*)((char*)d_ws + (size_t)N * 256 * sizeof(bf16)); // [N][128] f32

    (void)n_in; (void)out_size; (void)ws_size;

    cur_kernel<<<nblk, 256, 0, stream>>>(z, cw1, cb1, cw2, cb2, nw1, nb1, feat, u1, N);
    nbr_kernel<<<512, 256, 0, stream>>>(zn, u1, nw1, nw2, nb2, feat, NP);
    out_kernel<<<nblk, 256, 0, stream>>>(feat, ow, ob, out, N);
}